// Round 1
// baseline (416.296 us; speedup 1.0000x reference)
//
#include <hip/hip_runtime.h>

// out[i][j] = A[i] * B[i][j]; N=8192 rows, M=8192 cols, fp32.
// Memory-bound: 512 MiB moved -> ~85us floor at 6.3 TB/s.
// One thread per float4 (16B/lane coalescing sweet spot).
__global__ __launch_bounds__(256) void rowscale_f4_kernel(
    const float* __restrict__ A,
    const float4* __restrict__ B4,
    float4* __restrict__ O4,
    int total4,
    int row_shift)   // log2(M/4); M=8192 -> 11
{
    int idx = blockIdx.x * blockDim.x + threadIdx.x;
    if (idx >= total4) return;
    int row = idx >> row_shift;
    float a = A[row];
    float4 b = B4[idx];
    float4 r;
    r.x = a * b.x;
    r.y = a * b.y;
    r.z = a * b.z;
    r.w = a * b.w;
    O4[idx] = r;
}

// Fallback for non-multiple-of-4 / non-pow2 geometry (not expected here).
__global__ __launch_bounds__(256) void rowscale_scalar_kernel(
    const float* __restrict__ A,
    const float* __restrict__ B,
    float* __restrict__ O,
    long long total,
    int M)
{
    long long idx = (long long)blockIdx.x * blockDim.x + threadIdx.x;
    if (idx >= total) return;
    int row = (int)(idx / M);
    O[idx] = A[row] * B[idx];
}

extern "C" void kernel_launch(void* const* d_in, const int* in_sizes, int n_in,
                              void* d_out, int out_size, void* d_ws, size_t ws_size,
                              hipStream_t stream) {
    const float* A = (const float*)d_in[0];
    const float* B = (const float*)d_in[1];
    float* O = (float*)d_out;

    const int N = in_sizes[0];
    const long long total = in_sizes[1];  // N*M
    const int M = (int)(total / N);

    // Fast path: M divisible by 4 and M/4 a power of two (true for 8192).
    const int m4 = M / 4;
    const bool pow2 = (M % 4 == 0) && ((m4 & (m4 - 1)) == 0);
    if (pow2) {
        int shift = 0;
        while ((1 << shift) < m4) shift++;
        const int total4 = (int)(total / 4);
        const int block = 256;
        const int grid = (total4 + block - 1) / block;
        rowscale_f4_kernel<<<grid, block, 0, stream>>>(
            A, (const float4*)B, (float4*)O, total4, shift);
    } else {
        const int block = 256;
        const long long grid = (total + block - 1) / block;
        rowscale_scalar_kernel<<<(int)grid, block, 0, stream>>>(A, B, O, total, M);
    }
}